// Round 1
// baseline (301.756 us; speedup 1.0000x reference)
//
#include <hip/hip_runtime.h>
#include <math.h>

#define N_NODES 100000
#define N_EDGES 1600000
#define IN_CH 128
#define HEADS 4
#define HEAD_DIM 16
#define OUT_CH 64
#define NEG_SLOPE 0.2f
#define EPS 1e-8f
#define SCAN_BLOCKS ((N_NODES + 255) / 256)   // 391
#define NCOPY 8                                // one deg copy per XCD

typedef _Float16 f16x8 __attribute__((ext_vector_type(8)));
typedef _Float16 f16x4 __attribute__((ext_vector_type(4)));
typedef float    f32x4 __attribute__((ext_vector_type(4)));

// ---------------------------------------------------------------------------
// Prep: wsd[8][128] fp32 — w_s rows 0-3, w_d rows 4-7.
// ---------------------------------------------------------------------------
__global__ __launch_bounds__(128) void wsd_kernel(
    const float* __restrict__ W, const float* __restrict__ a,
    float* __restrict__ wsd)
{
    int k = threadIdx.x;   // 0..127
#pragma unroll
    for (int hd = 0; hd < 4; hd++) {
        float ss = 0.f, dd = 0.f;
#pragma unroll
        for (int c = 0; c < 16; c++) {
            float wv = W[(hd * 16 + c) * IN_CH + k];
            ss += a[hd * 32 + c] * wv;
            dd += a[hd * 32 + 16 + c] * wv;
        }
        wsd[hd * IN_CH + k] = ss;
        wsd[(4 + hd) * IN_CH + k] = dd;
    }
}

__device__ inline f16x8 cvt8(const float* p) {
    float4 lo = ((const float4*)p)[0];
    float4 hi = ((const float4*)p)[1];
    f16x8 f;
    f[0] = (_Float16)lo.x; f[1] = (_Float16)lo.y;
    f[2] = (_Float16)lo.z; f[3] = (_Float16)lo.w;
    f[4] = (_Float16)hi.x; f[5] = (_Float16)hi.y;
    f[6] = (_Float16)hi.z; f[7] = (_Float16)hi.w;
    return f;
}

// ---------------------------------------------------------------------------
// GEMM via MFMA 16x16x32 f16. Block = 4 waves x 32 nodes = 128 nodes.
// N-tile 4 carries alpha (wsd rows; cols 0-3 = a_src heads, 4-7 = a_dst).
// ---------------------------------------------------------------------------
__global__ __launch_bounds__(256) void gemm_alpha_kernel(
    const float* __restrict__ x,      // [N_NODES, 128]
    const float* __restrict__ W,      // [64, 128]
    const float* __restrict__ wsd,    // [8, 128]
    _Float16* __restrict__ h,         // [N_NODES, 64] fp16
    float* __restrict__ alpha_src,    // [N_NODES, 4]
    float* __restrict__ alpha_dst)    // [N_NODES, 4]
{
    const int wv = threadIdx.x >> 6;
    const int lane = threadIdx.x & 63;
    const int col = lane & 15;
    const int quad = lane >> 4;
    const int node_base = blockIdx.x * 128 + wv * 32;

    f16x8 bfrag[5][4];
#pragma unroll
    for (int nt = 0; nt < 4; nt++) {
        const float* src = W + (nt * 16 + col) * IN_CH;
#pragma unroll
        for (int ks = 0; ks < 4; ks++)
            bfrag[nt][ks] = cvt8(src + ks * 32 + quad * 8);
    }
    {
        const float* src = wsd + (col < 8 ? col : 0) * IN_CH;
#pragma unroll
        for (int ks = 0; ks < 4; ks++) {
            f16x8 f = cvt8(src + ks * 32 + quad * 8);
            if (col >= 8) {
                f16x8 z = {};
                f = z;
            }
            bfrag[4][ks] = f;
        }
    }

#pragma unroll
    for (int mt = 0; mt < 2; mt++) {
        int row_node = node_base + mt * 16 + col;
        int rn = row_node < N_NODES ? row_node : N_NODES - 1;
        const float* xrow = x + (long long)rn * IN_CH;

        f16x8 afrag[4];
#pragma unroll
        for (int ks = 0; ks < 4; ks++)
            afrag[ks] = cvt8(xrow + ks * 32 + quad * 8);

        f32x4 acc[5];
#pragma unroll
        for (int nt = 0; nt < 5; nt++) {
            f32x4 z = {0.f, 0.f, 0.f, 0.f};
            acc[nt] = z;
        }
#pragma unroll
        for (int ks = 0; ks < 4; ks++)
#pragma unroll
            for (int nt = 0; nt < 5; nt++)
                acc[nt] = __builtin_amdgcn_mfma_f32_16x16x32_f16(
                    afrag[ks], bfrag[nt][ks], acc[nt], 0, 0, 0);

#pragma unroll
        for (int r = 0; r < 4; r++) {
            int node = node_base + mt * 16 + quad * 4 + r;
            if (node < N_NODES) {
#pragma unroll
                for (int nt = 0; nt < 4; nt++)
                    h[(long long)node * OUT_CH + nt * 16 + col] = (_Float16)acc[nt][r];
                if (col < 4)      alpha_src[node * HEADS + col]     = acc[4][r];
                else if (col < 8) alpha_dst[node * HEADS + col - 4] = acc[4][r];
            }
        }
    }
}

// ---------------------------------------------------------------------------
// CSR build with XCD-split histogram.
//   hist: WORKGROUP-scope atomics into deg8[xcc][dst]. The scope keeps the
//         RMW in the XCD-local L2 (no sc1 -> no memory-side round trip, which
//         rocprof showed as 51 MB of 32B-granular WRITE traffic and 64 us of
//         latency-bound stall). Correct regardless of dispatch mapping: the
//         copy index is the *physical* XCC_ID, so all accessors of copy c are
//         on XCD c, and L2 is XCD c's shared atomic point. Copy id is packed
//         into rank's high bits so fill doesn't depend on the mapping.
//   combine: off8[c][n] = prefix over copies; deg[n] = total
//   scan (3-phase) -> ptr
//   fill: slot = ptr[d] + off8[c][d] + r   (c, r decoded from rank[e])
// ---------------------------------------------------------------------------
__global__ __launch_bounds__(256) void hist_rank_kernel(
    const int* __restrict__ ei, int* __restrict__ deg8, int* __restrict__ rank)
{
    int e = blockIdx.x * 256 + threadIdx.x;
    if (e >= N_EDGES) return;
    unsigned xcc;
    asm volatile("s_getreg_b32 %0, hwreg(HW_REG_XCC_ID)" : "=s"(xcc));
    int c = (int)(xcc & (NCOPY - 1));
    int d = ei[N_EDGES + e];
    int r = __hip_atomic_fetch_add(&deg8[c * N_NODES + d], 1,
                                   __ATOMIC_RELAXED, __HIP_MEMORY_SCOPE_WORKGROUP);
    rank[e] = (c << 28) | r;
}

__global__ __launch_bounds__(256) void combine_kernel(
    const int* __restrict__ deg8, int* __restrict__ off8, int* __restrict__ deg)
{
    int n = blockIdx.x * 256 + threadIdx.x;
    if (n >= N_NODES) return;
    int run = 0;
#pragma unroll
    for (int c = 0; c < NCOPY; c++) {
        off8[c * N_NODES + n] = run;
        run += deg8[c * N_NODES + n];
    }
    deg[n] = run;
}

__global__ __launch_bounds__(256) void scan_reduce_kernel(
    const int* __restrict__ deg, int* __restrict__ blockSums)
{
    __shared__ int sdata[256];
    int t = threadIdx.x;
    int i = blockIdx.x * 256 + t;
    sdata[t] = (i < N_NODES) ? deg[i] : 0;
    __syncthreads();
    for (int off = 128; off > 0; off >>= 1) {
        if (t < off) sdata[t] += sdata[t + off];
        __syncthreads();
    }
    if (t == 0) blockSums[blockIdx.x] = sdata[0];
}

__global__ __launch_bounds__(512) void scan_blocksums_kernel(
    const int* __restrict__ blockSums, int* __restrict__ blockOffsets,
    int* __restrict__ ptr)
{
    __shared__ int part[512];
    int t = threadIdx.x;
    int v = (t < SCAN_BLOCKS) ? blockSums[t] : 0;
    part[t] = v;
    __syncthreads();
    for (int off = 1; off < 512; off <<= 1) {
        int xv = (t >= off) ? part[t - off] : 0;
        __syncthreads();
        part[t] += xv;
        __syncthreads();
    }
    if (t < SCAN_BLOCKS) blockOffsets[t] = part[t] - v;  // exclusive
    if (t == 0) ptr[N_NODES] = N_EDGES;
}

__global__ __launch_bounds__(256) void scan_final_kernel(
    const int* __restrict__ deg, const int* __restrict__ blockOffsets,
    int* __restrict__ ptr)
{
    __shared__ int part[256];
    int t = threadIdx.x;
    int i = blockIdx.x * 256 + t;
    int v = (i < N_NODES) ? deg[i] : 0;
    part[t] = v;
    __syncthreads();
    for (int off = 1; off < 256; off <<= 1) {
        int xv = (t >= off) ? part[t - off] : 0;
        __syncthreads();
        part[t] += xv;
        __syncthreads();
    }
    if (i < N_NODES) ptr[i] = blockOffsets[blockIdx.x] + part[t] - v;
}

__global__ __launch_bounds__(256) void fill_kernel(
    const int* __restrict__ ei, const float* __restrict__ ew,
    const int* __restrict__ rank, const int* __restrict__ ptr,
    const int* __restrict__ off8, long long* __restrict__ csr)
{
    int e = blockIdx.x * 256 + threadIdx.x;
    if (e >= N_EDGES) return;
    int s = ei[e];
    int d = ei[N_EDGES + e];
    int rr = rank[e];
    int c = rr >> 28;              // copy id packed by hist_rank
    int r = rr & 0x0FFFFFFF;
    int idx = ptr[d] + off8[c * N_NODES + d] + r;
    long long v = (long long)((unsigned long long)__float_as_uint(ew[e]) << 32)
                | (unsigned int)s;
    __builtin_nontemporal_store(v, &csr[idx]);   // skip write-allocate on scatter
}

// ---------------------------------------------------------------------------
// Aggregate v3: one wave per dst node, quarter-wave edge parallelism.
// ---------------------------------------------------------------------------
__global__ __launch_bounds__(256) void aggregate_kernel(
    const int* __restrict__ ptr,
    const int2* __restrict__ csr,
    const float4* __restrict__ alpha_src4,   // [N_NODES]
    const float4* __restrict__ alpha_dst4,   // [N_NODES]
    const _Float16* __restrict__ h,          // [N_NODES, 64]
    float* __restrict__ out)
{
    __shared__ float4 sev[4][64];   // per-wave ev4 staging
    __shared__ int    ssc[4][64];   // per-wave src staging

    const int wv = threadIdx.x >> 6;
    const int lane = threadIdx.x & 63;
    const int n = blockIdx.x * 4 + wv;
    if (n >= N_NODES) return;
    const int q = lane >> 4;          // quarter 0..3
    const int cg = lane & 15;         // channel group: ch 4*cg..4*cg+3
    const int hsel = cg >> 2;         // head of this channel group

    const int beg = ptr[n];
    const int end = ptr[n + 1];
    const float4 ad4 = alpha_dst4[n];

    float4 acc = make_float4(0.f, 0.f, 0.f, 0.f);
    float denom = 0.f;
    float4* sev_w = sev[wv];
    int* ssc_w = ssc[wv];

    for (int base = beg; base < end; base += 64) {
        int cnt = min(64, end - base);
        int s_l = 0;
        float4 e4 = make_float4(0.f, 0.f, 0.f, 0.f);
        if (lane < cnt) {
            int2 pr = csr[base + lane];
            s_l = pr.x;
            float w = __int_as_float(pr.y);
            float4 as = alpha_src4[s_l];
            float t0 = as.x + ad4.x; t0 = (t0 > 0.f ? t0 : NEG_SLOPE * t0) * w;
            float t1 = as.y + ad4.y; t1 = (t1 > 0.f ? t1 : NEG_SLOPE * t1) * w;
            float t2 = as.z + ad4.z; t2 = (t2 > 0.f ? t2 : NEG_SLOPE * t2) * w;
            float t3 = as.w + ad4.w; t3 = (t3 > 0.f ? t3 : NEG_SLOPE * t3) * w;
            e4 = make_float4(__expf(t0), __expf(t1), __expf(t2), __expf(t3));
        }
        sev_w[lane] = e4;         // intra-wave LDS, no barrier needed
        ssc_w[lane] = s_l;

        int iters = (cnt + 3) >> 2;
        for (int j0 = 0; j0 < iters; j0 += 2) {
            int idx0 = j0 * 4 + q;
            int idx1 = idx0 + 4;          // may pass cnt: contributes zero
            int s0 = ssc_w[idx0];
            int s1 = ssc_w[idx1];
            float ev0 = ((const float*)&sev_w[idx0])[hsel];
            float ev1 = ((const float*)&sev_w[idx1])[hsel];
            f16x4 h0 = *(const f16x4*)(h + s0 * OUT_CH + cg * 4);
            f16x4 h1 = *(const f16x4*)(h + s1 * OUT_CH + cg * 4);
            acc.x += ev0 * (float)h0[0] + ev1 * (float)h1[0];
            acc.y += ev0 * (float)h0[1] + ev1 * (float)h1[1];
            acc.z += ev0 * (float)h0[2] + ev1 * (float)h1[2];
            acc.w += ev0 * (float)h0[3] + ev1 * (float)h1[3];
            denom += ev0 + ev1;
        }
    }

    // combine the 4 quarters (xor butterfly)
    denom += __shfl_xor(denom, 16);
    denom += __shfl_xor(denom, 32);
    acc.x += __shfl_xor(acc.x, 16);  acc.x += __shfl_xor(acc.x, 32);
    acc.y += __shfl_xor(acc.y, 16);  acc.y += __shfl_xor(acc.y, 32);
    acc.z += __shfl_xor(acc.z, 16);  acc.z += __shfl_xor(acc.z, 32);
    acc.w += __shfl_xor(acc.w, 16);  acc.w += __shfl_xor(acc.w, 32);

    if (lane < 16) {
        float inv = 1.f / (denom + EPS);
        float4 r = make_float4(acc.x * inv, acc.y * inv, acc.z * inv, acc.w * inv);
        ((float4*)(out + (long long)n * OUT_CH))[cg] = r;
    }
}

extern "C" void kernel_launch(void* const* d_in, const int* in_sizes, int n_in,
                              void* d_out, int out_size, void* d_ws, size_t ws_size,
                              hipStream_t stream) {
    const float* x  = (const float*)d_in[0];
    const int*   ei = (const int*)d_in[1];     // int32 per harness contract
    const float* ew = (const float*)d_in[2];
    const float* W  = (const float*)d_in[3];
    const float* a  = (const float*)d_in[4];
    float* out = (float*)d_out;

    // workspace layout (all 16B-aligned)
    char* p = (char*)d_ws;
    _Float16* h      = (_Float16*)p; p += (size_t)N_NODES * OUT_CH * 2;  // 12.8 MB
    float* alpha_src = (float*)p;  p += (size_t)N_NODES * HEADS * 4;     // 1.6 MB
    float* alpha_dst = (float*)p;  p += (size_t)N_NODES * HEADS * 4;     // 1.6 MB
    float* wsd       = (float*)p;  p += (size_t)8 * IN_CH * 4;           // 4 KB
    int*   deg8      = (int*)p;    p += (size_t)NCOPY * N_NODES * 4;     // 3.2 MB
    int*   off8      = (int*)p;    p += (size_t)NCOPY * N_NODES * 4;     // 3.2 MB
    int*   deg       = (int*)p;    p += (size_t)N_NODES * 4;             // 0.4 MB
    int*   ptr       = (int*)p;    p += (size_t)(N_NODES + 4) * 4;       // 0.4 MB
    int*   rank      = (int*)p;    p += (size_t)N_EDGES * 4;             // 6.4 MB
    int*   blockSums = (int*)p;    p += (size_t)((SCAN_BLOCKS + 3) & ~3) * 4;
    int*   blockOffs = (int*)p;    p += (size_t)((SCAN_BLOCKS + 3) & ~3) * 4;
    long long* csr   = (long long*)p;                                    // 12.8 MB

    hipMemsetAsync(deg8, 0, (size_t)NCOPY * N_NODES * sizeof(int), stream);

    wsd_kernel<<<1, 128, 0, stream>>>(W, a, wsd);
    hist_rank_kernel<<<(N_EDGES + 255) / 256, 256, 0, stream>>>(ei, deg8, rank);
    gemm_alpha_kernel<<<(N_NODES + 127) / 128, 256, 0, stream>>>(x, W, wsd, h, alpha_src, alpha_dst);
    combine_kernel<<<(N_NODES + 255) / 256, 256, 0, stream>>>(deg8, off8, deg);
    scan_reduce_kernel<<<SCAN_BLOCKS, 256, 0, stream>>>(deg, blockSums);
    scan_blocksums_kernel<<<1, 512, 0, stream>>>(blockSums, blockOffs, ptr);
    scan_final_kernel<<<SCAN_BLOCKS, 256, 0, stream>>>(deg, blockOffs, ptr);
    fill_kernel<<<(N_EDGES + 255) / 256, 256, 0, stream>>>(ei, ew, rank, ptr, off8, csr);
    aggregate_kernel<<<(N_NODES + 3) / 4, 256, 0, stream>>>(
        ptr, (const int2*)csr, (const float4*)alpha_src, (const float4*)alpha_dst, h, out);
}

// Round 2
// 222.367 us; speedup vs baseline: 1.3570x; 1.3570x over previous
//
#include <hip/hip_runtime.h>
#include <math.h>

#define N_NODES 100000
#define N_EDGES 1600000
#define IN_CH 128
#define HEADS 4
#define HEAD_DIM 16
#define OUT_CH 64
#define NEG_SLOPE 0.2f
#define EPS 1e-8f

// ---- counting-sort CSR build parameters ----
#define NBUCK 391                 // coarse buckets of 256 nodes: (100000+255)/256
#define NBLK1 256                 // pass-1/3 blocks
#define CHUNK (N_EDGES / NBLK1)   // 6250 edges per block (exact)
#define CAP 4608                  // LDS staging bound per bucket (mean 4092 + 8 sigma)

typedef _Float16 f16x8 __attribute__((ext_vector_type(8)));
typedef _Float16 f16x4 __attribute__((ext_vector_type(4)));
typedef float    f32x4 __attribute__((ext_vector_type(4)));

// ---------------------------------------------------------------------------
// Prep: wsd[8][128] fp32 — w_s rows 0-3, w_d rows 4-7.
// ---------------------------------------------------------------------------
__global__ __launch_bounds__(128) void wsd_kernel(
    const float* __restrict__ W, const float* __restrict__ a,
    float* __restrict__ wsd)
{
    int k = threadIdx.x;   // 0..127
#pragma unroll
    for (int hd = 0; hd < 4; hd++) {
        float ss = 0.f, dd = 0.f;
#pragma unroll
        for (int c = 0; c < 16; c++) {
            float wv = W[(hd * 16 + c) * IN_CH + k];
            ss += a[hd * 32 + c] * wv;
            dd += a[hd * 32 + 16 + c] * wv;
        }
        wsd[hd * IN_CH + k] = ss;
        wsd[(4 + hd) * IN_CH + k] = dd;
    }
}

__device__ inline f16x8 cvt8(const float* p) {
    float4 lo = ((const float4*)p)[0];
    float4 hi = ((const float4*)p)[1];
    f16x8 f;
    f[0] = (_Float16)lo.x; f[1] = (_Float16)lo.y;
    f[2] = (_Float16)lo.z; f[3] = (_Float16)lo.w;
    f[4] = (_Float16)hi.x; f[5] = (_Float16)hi.y;
    f[6] = (_Float16)hi.z; f[7] = (_Float16)hi.w;
    return f;
}

// ---------------------------------------------------------------------------
// GEMM via MFMA 16x16x32 f16. Block = 4 waves x 32 nodes = 128 nodes.
// N-tile 4 carries alpha (wsd rows; cols 0-3 = a_src heads, 4-7 = a_dst).
// ---------------------------------------------------------------------------
__global__ __launch_bounds__(256) void gemm_alpha_kernel(
    const float* __restrict__ x,      // [N_NODES, 128]
    const float* __restrict__ W,      // [64, 128]
    const float* __restrict__ wsd,    // [8, 128]
    _Float16* __restrict__ h,         // [N_NODES, 64] fp16
    float* __restrict__ alpha_src,    // [N_NODES, 4]
    float* __restrict__ alpha_dst)    // [N_NODES, 4]
{
    const int wv = threadIdx.x >> 6;
    const int lane = threadIdx.x & 63;
    const int col = lane & 15;
    const int quad = lane >> 4;
    const int node_base = blockIdx.x * 128 + wv * 32;

    f16x8 bfrag[5][4];
#pragma unroll
    for (int nt = 0; nt < 4; nt++) {
        const float* src = W + (nt * 16 + col) * IN_CH;
#pragma unroll
        for (int ks = 0; ks < 4; ks++)
            bfrag[nt][ks] = cvt8(src + ks * 32 + quad * 8);
    }
    {
        const float* src = wsd + (col < 8 ? col : 0) * IN_CH;
#pragma unroll
        for (int ks = 0; ks < 4; ks++) {
            f16x8 f = cvt8(src + ks * 32 + quad * 8);
            if (col >= 8) {
                f16x8 z = {};
                f = z;
            }
            bfrag[4][ks] = f;
        }
    }

#pragma unroll
    for (int mt = 0; mt < 2; mt++) {
        int row_node = node_base + mt * 16 + col;
        int rn = row_node < N_NODES ? row_node : N_NODES - 1;
        const float* xrow = x + (long long)rn * IN_CH;

        f16x8 afrag[4];
#pragma unroll
        for (int ks = 0; ks < 4; ks++)
            afrag[ks] = cvt8(xrow + ks * 32 + quad * 8);

        f32x4 acc[5];
#pragma unroll
        for (int nt = 0; nt < 5; nt++) {
            f32x4 z = {0.f, 0.f, 0.f, 0.f};
            acc[nt] = z;
        }
#pragma unroll
        for (int ks = 0; ks < 4; ks++)
#pragma unroll
            for (int nt = 0; nt < 5; nt++)
                acc[nt] = __builtin_amdgcn_mfma_f32_16x16x32_f16(
                    afrag[ks], bfrag[nt][ks], acc[nt], 0, 0, 0);

#pragma unroll
        for (int r = 0; r < 4; r++) {
            int node = node_base + mt * 16 + quad * 4 + r;
            if (node < N_NODES) {
#pragma unroll
                for (int nt = 0; nt < 4; nt++)
                    h[(long long)node * OUT_CH + nt * 16 + col] = (_Float16)acc[nt][r];
                if (col < 4)      alpha_src[node * HEADS + col]     = acc[4][r];
                else if (col < 8) alpha_dst[node * HEADS + col - 4] = acc[4][r];
            }
        }
    }
}

// ---------------------------------------------------------------------------
// CSR build: two-level counting sort. ZERO global atomics (the memory-side
// atomic pipe caps at ~25 G RMW/s = 64 us for 1.6M edges; LDS ds_add is
// per-CU and free by comparison). All ranking via LDS atomics; final csr
// write is LDS-staged and fully coalesced.
//
//   K1 coarse_count : per-block LDS hist over 391 buckets (dst>>8)
//   K2a partial_scan: per-bucket exclusive prefix over the 256 blocks
//   K2b bucket_offs : exclusive scan of bucket totals -> bucketStart
//   K3 coarse_scatter: LDS cursors (absolute) -> tmp[] bucket-sorted,
//                      packed u64 = w<<32 | dloc<<17 | src
//   K4 finalize     : per-bucket count/scan -> ptr[] ; stage slots in LDS
//                      -> coalesced csr write. CAP overflow falls back to
//                      direct global store (correct, just slower).
// ---------------------------------------------------------------------------
__global__ __launch_bounds__(256) void coarse_count_kernel(
    const int* __restrict__ ei, int* __restrict__ counts /*[NBUCK][NBLK1]*/)
{
    __shared__ int cnt[NBUCK];
    for (int j = threadIdx.x; j < NBUCK; j += 256) cnt[j] = 0;
    __syncthreads();
    const int base = blockIdx.x * CHUNK;
    for (int i = threadIdx.x; i < CHUNK; i += 256) {
        int d = ei[N_EDGES + base + i];
        atomicAdd(&cnt[d >> 8], 1);          // LDS atomic
    }
    __syncthreads();
    for (int j = threadIdx.x; j < NBUCK; j += 256)
        counts[j * NBLK1 + blockIdx.x] = cnt[j];
}

__global__ __launch_bounds__(256) void partial_scan_kernel(
    int* __restrict__ counts, int* __restrict__ totals)
{
    __shared__ int s[256];
    const int j = blockIdx.x;
    const int t = threadIdx.x;
    int v = counts[j * NBLK1 + t];
    s[t] = v;
    __syncthreads();
    for (int off = 1; off < 256; off <<= 1) {
        int x = (t >= off) ? s[t - off] : 0;
        __syncthreads();
        s[t] += x;
        __syncthreads();
    }
    counts[j * NBLK1 + t] = s[t] - v;        // exclusive partial prefix
    if (t == 255) totals[j] = s[255];
}

__global__ __launch_bounds__(512) void bucket_offsets_kernel(
    const int* __restrict__ totals, int* __restrict__ bucketStart,
    int* __restrict__ ptr)
{
    __shared__ int part[512];
    const int t = threadIdx.x;
    int v = (t < NBUCK) ? totals[t] : 0;
    part[t] = v;
    __syncthreads();
    for (int off = 1; off < 512; off <<= 1) {
        int x = (t >= off) ? part[t - off] : 0;
        __syncthreads();
        part[t] += x;
        __syncthreads();
    }
    if (t < NBUCK) bucketStart[t] = part[t] - v;     // exclusive
    if (t == 0) { bucketStart[NBUCK] = N_EDGES; ptr[N_NODES] = N_EDGES; }
}

__global__ __launch_bounds__(256) void coarse_scatter_kernel(
    const int* __restrict__ ei, const float* __restrict__ ew,
    const int* __restrict__ counts, const int* __restrict__ bucketStart,
    unsigned long long* __restrict__ tmp)
{
    __shared__ int cur[NBUCK];
    const int b = blockIdx.x;
    for (int j = threadIdx.x; j < NBUCK; j += 256)
        cur[j] = bucketStart[j] + counts[j * NBLK1 + b];   // absolute cursor
    __syncthreads();
    const int base = b * CHUNK;
    for (int i = threadIdx.x; i < CHUNK; i += 256) {
        int e = base + i;
        int s = ei[e];
        int d = ei[N_EDGES + e];
        float w = ew[e];
        int pos = atomicAdd(&cur[d >> 8], 1);              // LDS atomic
        unsigned long long pk = ((unsigned long long)__float_as_uint(w) << 32)
                              | ((unsigned)(d & 255) << 17) | (unsigned)s;
        tmp[pos] = pk;   // per-(block,bucket) runs ~128B contiguous
    }
}

__global__ __launch_bounds__(256) void finalize_kernel(
    const unsigned long long* __restrict__ tmp,
    const int* __restrict__ bucketStart,
    long long* __restrict__ csr, int* __restrict__ ptr)
{
    __shared__ int cnt[256];
    __shared__ int offs[256];
    __shared__ unsigned long long stage[CAP];
    const int j = blockIdx.x;
    const int t = threadIdx.x;
    const int beg = bucketStart[j];
    const int end = bucketStart[j + 1];
    const int len = end - beg;

    cnt[t] = 0;
    __syncthreads();
    for (int i = t; i < len; i += 256) {
        int dloc = (int)((tmp[beg + i] >> 17) & 255);
        atomicAdd(&cnt[dloc], 1);
    }
    __syncthreads();
    int v = cnt[t];
    // in-place Hillis-Steele inclusive scan
    for (int off = 1; off < 256; off <<= 1) {
        int x = (t >= off) ? cnt[t - off] : 0;
        __syncthreads();
        cnt[t] += x;
        __syncthreads();
    }
    int excl = cnt[t] - v;
    int node = j * 256 + t;
    if (node < N_NODES) ptr[node] = beg + excl;
    offs[t] = excl;                  // cursors (bucket-local)
    __syncthreads();
    for (int i = t; i < len; i += 256) {
        unsigned long long pk = tmp[beg + i];
        int dloc = (int)((pk >> 17) & 255);
        int pos = atomicAdd(&offs[dloc], 1);
        unsigned long long vv = (pk & 0xFFFFFFFF00000000ull) | (pk & 0x1FFFFull);
        if (pos < CAP) stage[pos] = vv;
        else ((unsigned long long*)csr)[beg + pos] = vv;   // overflow fallback
    }
    __syncthreads();
    for (int i = t; i < len && i < CAP; i += 256)
        ((unsigned long long*)csr)[beg + i] = stage[i];    // coalesced
}

// ---------------------------------------------------------------------------
// Aggregate v3: one wave per dst node, quarter-wave edge parallelism.
// ---------------------------------------------------------------------------
__global__ __launch_bounds__(256) void aggregate_kernel(
    const int* __restrict__ ptr,
    const int2* __restrict__ csr,
    const float4* __restrict__ alpha_src4,   // [N_NODES]
    const float4* __restrict__ alpha_dst4,   // [N_NODES]
    const _Float16* __restrict__ h,          // [N_NODES, 64]
    float* __restrict__ out)
{
    __shared__ float4 sev[4][64];   // per-wave ev4 staging
    __shared__ int    ssc[4][64];   // per-wave src staging

    const int wv = threadIdx.x >> 6;
    const int lane = threadIdx.x & 63;
    const int n = blockIdx.x * 4 + wv;
    if (n >= N_NODES) return;
    const int q = lane >> 4;          // quarter 0..3
    const int cg = lane & 15;         // channel group: ch 4*cg..4*cg+3
    const int hsel = cg >> 2;         // head of this channel group

    const int beg = ptr[n];
    const int end = ptr[n + 1];
    const float4 ad4 = alpha_dst4[n];

    float4 acc = make_float4(0.f, 0.f, 0.f, 0.f);
    float denom = 0.f;
    float4* sev_w = sev[wv];
    int* ssc_w = ssc[wv];

    for (int base = beg; base < end; base += 64) {
        int cnt = min(64, end - base);
        int s_l = 0;
        float4 e4 = make_float4(0.f, 0.f, 0.f, 0.f);
        if (lane < cnt) {
            int2 pr = csr[base + lane];
            s_l = pr.x;
            float w = __int_as_float(pr.y);
            float4 as = alpha_src4[s_l];
            float t0 = as.x + ad4.x; t0 = (t0 > 0.f ? t0 : NEG_SLOPE * t0) * w;
            float t1 = as.y + ad4.y; t1 = (t1 > 0.f ? t1 : NEG_SLOPE * t1) * w;
            float t2 = as.z + ad4.z; t2 = (t2 > 0.f ? t2 : NEG_SLOPE * t2) * w;
            float t3 = as.w + ad4.w; t3 = (t3 > 0.f ? t3 : NEG_SLOPE * t3) * w;
            e4 = make_float4(__expf(t0), __expf(t1), __expf(t2), __expf(t3));
        }
        sev_w[lane] = e4;         // intra-wave LDS, no barrier needed
        ssc_w[lane] = s_l;

        int iters = (cnt + 3) >> 2;
        for (int j0 = 0; j0 < iters; j0 += 2) {
            int idx0 = j0 * 4 + q;
            int idx1 = idx0 + 4;          // may pass cnt: contributes zero
            int s0 = ssc_w[idx0];
            int s1 = ssc_w[idx1];
            float ev0 = ((const float*)&sev_w[idx0])[hsel];
            float ev1 = ((const float*)&sev_w[idx1])[hsel];
            f16x4 h0 = *(const f16x4*)(h + s0 * OUT_CH + cg * 4);
            f16x4 h1 = *(const f16x4*)(h + s1 * OUT_CH + cg * 4);
            acc.x += ev0 * (float)h0[0] + ev1 * (float)h1[0];
            acc.y += ev0 * (float)h0[1] + ev1 * (float)h1[1];
            acc.z += ev0 * (float)h0[2] + ev1 * (float)h1[2];
            acc.w += ev0 * (float)h0[3] + ev1 * (float)h1[3];
            denom += ev0 + ev1;
        }
    }

    // combine the 4 quarters (xor butterfly)
    denom += __shfl_xor(denom, 16);
    denom += __shfl_xor(denom, 32);
    acc.x += __shfl_xor(acc.x, 16);  acc.x += __shfl_xor(acc.x, 32);
    acc.y += __shfl_xor(acc.y, 16);  acc.y += __shfl_xor(acc.y, 32);
    acc.z += __shfl_xor(acc.z, 16);  acc.z += __shfl_xor(acc.z, 32);
    acc.w += __shfl_xor(acc.w, 16);  acc.w += __shfl_xor(acc.w, 32);

    if (lane < 16) {
        float inv = 1.f / (denom + EPS);
        float4 r = make_float4(acc.x * inv, acc.y * inv, acc.z * inv, acc.w * inv);
        ((float4*)(out + (long long)n * OUT_CH))[cg] = r;
    }
}

extern "C" void kernel_launch(void* const* d_in, const int* in_sizes, int n_in,
                              void* d_out, int out_size, void* d_ws, size_t ws_size,
                              hipStream_t stream) {
    const float* x  = (const float*)d_in[0];
    const int*   ei = (const int*)d_in[1];     // int32 per harness contract
    const float* ew = (const float*)d_in[2];
    const float* W  = (const float*)d_in[3];
    const float* a  = (const float*)d_in[4];
    float* out = (float*)d_out;

    // workspace layout (all 16B-aligned)
    char* p = (char*)d_ws;
    _Float16* h      = (_Float16*)p; p += (size_t)N_NODES * OUT_CH * 2;   // 12.8 MB
    float* alpha_src = (float*)p;  p += (size_t)N_NODES * HEADS * 4;      // 1.6 MB
    float* alpha_dst = (float*)p;  p += (size_t)N_NODES * HEADS * 4;      // 1.6 MB
    float* wsd       = (float*)p;  p += (size_t)8 * IN_CH * 4;            // 4 KB
    int*   counts    = (int*)p;    p += (size_t)NBUCK * NBLK1 * 4;        // 400 KB
    int*   totals    = (int*)p;    p += (size_t)392 * 4;                  // 1.6 KB
    int*   bstart    = (int*)p;    p += (size_t)392 * 4;                  // 1.6 KB
    int*   ptr       = (int*)p;    p += (size_t)(N_NODES + 4) * 4;        // 0.4 MB
    unsigned long long* tmp = (unsigned long long*)p;
    p += (size_t)N_EDGES * 8;                                             // 12.8 MB
    long long* csr   = (long long*)p;                                     // 12.8 MB

    wsd_kernel<<<1, 128, 0, stream>>>(W, a, wsd);
    coarse_count_kernel<<<NBLK1, 256, 0, stream>>>(ei, counts);
    partial_scan_kernel<<<NBUCK, 256, 0, stream>>>(counts, totals);
    bucket_offsets_kernel<<<1, 512, 0, stream>>>(totals, bstart, ptr);
    gemm_alpha_kernel<<<(N_NODES + 127) / 128, 256, 0, stream>>>(x, W, wsd, h, alpha_src, alpha_dst);
    coarse_scatter_kernel<<<NBLK1, 256, 0, stream>>>(ei, ew, counts, bstart, tmp);
    finalize_kernel<<<NBUCK, 256, 0, stream>>>(tmp, bstart, csr, ptr);
    aggregate_kernel<<<(N_NODES + 3) / 4, 256, 0, stream>>>(
        ptr, (const int2*)csr, (const float4*)alpha_src, (const float4*)alpha_dst, h, out);
}